// Round 7
// baseline (211.782 us; speedup 1.0000x reference)
//
#include <hip/hip_runtime.h>
#include <math.h>

#define DD    768
#define NQ    400
#define NROWS 408          // 400 q rows + 8 m_proj rows
#define JD    6144         // J*D = 8*768
#define WSLICE 4718592     // I*D*E = 8*768*768 (stride between j slices of W)
#define EPSF  1e-8f
#define K2    2304         // split-bf16 packed K (3 segments of 768)

// ---------------- workspace layout (floats) ----------------
#define OFF_H     6144                    // [408][6144]
#define OFF_HM    (OFF_H + 408*6144)      // [64][768]  (j*8+i major)
#define OFF_MU    (OFF_HM + 64*768)       // [64]
#define OFF_MC2   (OFF_MU + 64)           // [64]
#define OFF_G     (OFF_MC2 + 64)          // [64][8]  Gram
#define OFF_DMQ   (OFF_G + 512)           // [400][64] dot(M_ji, q'_nj)
#define OFF_SQ0   (OFF_DMQ + 400*64)      // [400][8]  sum(q'_nj)
#define OFF_SQ20  (OFF_SQ0 + 400*8)       // [400][8]  sumsq(q'_nj)
#define OFF_HMT   (OFF_SQ20 + 400*8)      // [768][64] transposed hm
#define OFF_A2    (OFF_HMT + 768*64)      // [512][2304] bf16 (as u16)
#define OFF_B2    (OFF_A2 + 512*K2/2)     // [6144][2304] bf16 (as u16)

#define FOR8(M) M(0) M(1) M(2) M(3) M(4) M(5) M(6) M(7)

typedef __attribute__((ext_vector_type(8))) short short8v;
typedef __attribute__((ext_vector_type(4))) float float4v;

__device__ inline unsigned short f2bf(float x) {
    unsigned u = __float_as_uint(x);
    u += 0x7FFF + ((u >> 16) & 1);
    return (unsigned short)(u >> 16);
}
__device__ inline float bf2f(unsigned short h) {
    return __uint_as_float(((unsigned)h) << 16);
}

// ---------------- kernel 1: pack A'' = [hi | lo | hi]; rows 400..407 compute
// m_proj = m @ W_n in-register first (fused former k_mproj).
__global__ __launch_bounds__(256) void k_cvtA(const float* __restrict__ q,
                                              const float* __restrict__ m,
                                              const float* __restrict__ Wn,
                                              unsigned short* __restrict__ A2)
{
    const int r = blockIdx.x;          // 0..407
    const int tid = threadIdx.x;
    unsigned short* dst = A2 + (size_t)r * K2;
    if (r < NQ) {
        const float* src = q + (size_t)r * DD;
        #pragma unroll
        for (int u0 = 0; u0 < 3; ++u0) {
            const int u = u0 * 256 + tid;
            float x = src[u];
            unsigned short hi = f2bf(x);
            unsigned short lo = f2bf(x - bf2f(hi));
            dst[u] = hi; dst[DD + u] = lo; dst[2*DD + u] = hi;
        }
    } else {
        const int i = r - NQ;
        float a0 = 0.f, a1 = 0.f, a2 = 0.f;
        #pragma unroll 8
        for (int e = 0; e < DD; ++e) {
            const float mv = m[i*DD + e];
            const float* wr = Wn + (size_t)e * DD;
            a0 += mv * wr[tid];
            a1 += mv * wr[tid + 256];
            a2 += mv * wr[tid + 512];
        }
        #pragma unroll
        for (int u0 = 0; u0 < 3; ++u0) {
            const int u = u0 * 256 + tid;
            float x = (u0 == 0) ? a0 : (u0 == 1) ? a1 : a2;
            unsigned short hi = f2bf(x);
            unsigned short lo = f2bf(x - bf2f(hi));
            dst[u] = hi; dst[DD + u] = lo; dst[2*DD + u] = hi;
        }
    }
}

// ---------------- kernel 1c: pack B'' = [hi | hi | lo] from W[j,0,d,:] --------
__global__ __launch_bounds__(256) void k_cvtB(const float* __restrict__ W,
                                              unsigned short* __restrict__ B2)
{
    const int rw = blockIdx.x;         // 0..6143 = j*768 + d
    const int jj = rw / 768;
    const int d  = rw - jj * 768;
    const float* src = W + (size_t)jj * WSLICE + (size_t)d * DD;
    unsigned short* dst = B2 + (size_t)rw * K2;
    for (int u = threadIdx.x; u < DD; u += 256) {
        float x = src[u];
        unsigned short hi = f2bf(x);
        unsigned short lo = f2bf(x - bf2f(hi));
        dst[u] = hi; dst[DD + u] = hi; dst[2*DD + u] = lo;
    }
}

// ---------------- kernel 2: MFMA GEMM, 2-phase double-buffered LDS ------------
__global__ __launch_bounds__(256) void k_gemm_mfma(const unsigned short* __restrict__ A2,
                                                   const unsigned short* __restrict__ B2,
                                                   float* __restrict__ H)
{
    __shared__ __align__(16) unsigned short lds[2][16384];   // per buf: A [0,8192) B [8192,16384)
    const int tid = threadIdx.x;
    const int wv  = tid >> 6;
    const int ln  = tid & 63;
    const int c0  = blockIdx.x * 128;
    const int m0  = blockIdx.y * 128;
    const int wm  = (wv >> 1) * 64;
    const int wn  = (wv & 1) * 64;
    const unsigned short* Ap = A2 + (size_t)m0 * K2;
    const unsigned short* Bp = B2 + (size_t)c0 * K2;

    float4v acc[4][4];
    #pragma unroll
    for (int a = 0; a < 4; ++a)
        #pragma unroll
        for (int b = 0; b < 4; ++b)
            acc[a][b] = (float4v){0.f, 0.f, 0.f, 0.f};

#define STAGE(buf, kk0) { _Pragma("unroll")                                       \
    for (int qq = 0; qq < 4; ++qq) {                                              \
        const int idx = (qq << 8) + tid;                                          \
        const int row = idx >> 3;                                                 \
        const int ce  = ((idx & 7) ^ (row & 7)) << 3;                             \
        __builtin_amdgcn_global_load_lds(                                         \
            (const __attribute__((address_space(1))) void*)(Ap + (size_t)row * K2 + (kk0) + ce), \
            (__attribute__((address_space(3))) void*)(&lds[buf][idx * 8]), 16, 0, 0);            \
        __builtin_amdgcn_global_load_lds(                                         \
            (const __attribute__((address_space(1))) void*)(Bp + (size_t)row * K2 + (kk0) + ce), \
            (__attribute__((address_space(3))) void*)(&lds[buf][8192 + idx * 8]), 16, 0, 0);     \
    } }

#define COMPUTE(buf) { _Pragma("unroll")                                          \
    for (int s = 0; s < 2; ++s) {                                                 \
        short8v af[4], bf[4];                                                     \
        _Pragma("unroll")                                                         \
        for (int mi = 0; mi < 4; ++mi) {                                          \
            const int row = wm + mi * 16 + (ln & 15);                             \
            const int off = row * 64 + ((s * 32 + ((ln >> 4) * 8)) ^ ((row & 7) << 3)); \
            af[mi] = *reinterpret_cast<const short8v*>(&lds[buf][off]);           \
        }                                                                         \
        _Pragma("unroll")                                                         \
        for (int ni = 0; ni < 4; ++ni) {                                          \
            const int row = wn + ni * 16 + (ln & 15);                             \
            const int off = row * 64 + ((s * 32 + ((ln >> 4) * 8)) ^ ((row & 7) << 3)); \
            bf[ni] = *reinterpret_cast<const short8v*>(&lds[buf][8192 + off]);    \
        }                                                                         \
        _Pragma("unroll")                                                         \
        for (int mi = 0; mi < 4; ++mi)                                            \
            _Pragma("unroll")                                                     \
            for (int ni = 0; ni < 4; ++ni)                                        \
                acc[mi][ni] = __builtin_amdgcn_mfma_f32_16x16x32_bf16(af[mi], bf[ni], acc[mi][ni], 0, 0, 0); \
    } }

    STAGE(0, 0);
    __syncthreads();
    int cur = 0;
    for (int k0 = 64; k0 < K2; k0 += 64) {
        STAGE(cur ^ 1, k0);          // prefetch next tile (drained at the barrier below,
        COMPUTE(cur);                // after MFMA has covered most of the latency)
        __syncthreads();
        cur ^= 1;
    }
    COMPUTE(cur);
#undef STAGE
#undef COMPUTE

    #pragma unroll
    for (int mi = 0; mi < 4; ++mi) {
        #pragma unroll
        for (int r = 0; r < 4; ++r) {
            const int gr = m0 + wm + mi * 16 + (ln >> 4) * 4 + r;
            if (gr < NROWS) {
                #pragma unroll
                for (int ni = 0; ni < 4; ++ni)
                    H[(size_t)gr * JD + c0 + wn + ni * 16 + (ln & 15)] = acc[mi][ni][r];
            }
        }
    }
}

// ---------------- kernel 3: hat_m (+ transposed copy) + Pearson stats ---------
__global__ __launch_bounds__(256) void k_prep(const float* __restrict__ H,
                                              const float* __restrict__ b,
                                              float* __restrict__ hm,
                                              float* __restrict__ hmT,
                                              float* __restrict__ muM,
                                              float* __restrict__ mc2M)
{
    const int ji = blockIdx.x;
    const int j = ji >> 3, i = ji & 7;
    const int tid = threadIdx.x;
    const int lane = tid & 63, wave = tid >> 6;
    __shared__ float scr[4];
    __shared__ float smu;
    float vals[3];
    float s = 0.f;
    #pragma unroll
    for (int u = 0; u < 3; ++u) {
        const int d = u * 256 + tid;
        float x = H[(size_t)(NQ + i) * JD + j * DD + d] + b[(size_t)ji * DD + d];
        hm[(size_t)ji * DD + d] = x;
        hmT[(size_t)d * 64 + ji] = x;
        vals[u] = x;
        s += x;
    }
    #pragma unroll
    for (int off = 32; off; off >>= 1) s += __shfl_down(s, off);
    if (lane == 0) scr[wave] = s;
    __syncthreads();
    if (tid == 0) smu = (scr[0] + scr[1] + scr[2] + scr[3]) * (1.f / 768.f);
    __syncthreads();
    const float mu = smu;
    float s2 = 0.f;
    #pragma unroll
    for (int u = 0; u < 3; ++u) { float c = vals[u] - mu; s2 += c * c; }
    __syncthreads();
    #pragma unroll
    for (int off = 32; off; off >>= 1) s2 += __shfl_down(s2, off);
    if (lane == 0) scr[wave] = s2;
    __syncthreads();
    if (tid == 0) { muM[ji] = mu; mc2M[ji] = scr[0] + scr[1] + scr[2] + scr[3]; }
}

// ---------------- kernel 3b: Gram matrix G[ji][i'] = M_ji . M_ji' ----------------
__global__ __launch_bounds__(256) void k_gram(const float* __restrict__ hm,
                                              float* __restrict__ G)
{
    const int ji = blockIdx.x;          // 0..63
    const int j = ji >> 3;
    const int tid = threadIdx.x;
    const int lane = tid & 63, wave = tid >> 6;
    __shared__ float scr[8][4];
    const float a0 = hm[(size_t)ji*DD + tid];
    const float a1 = hm[(size_t)ji*DD + 256 + tid];
    const float a2 = hm[(size_t)ji*DD + 512 + tid];
#define GDOT(k) { const float* Bp = hm + (size_t)(j*8 + k)*DD + tid;             \
        float acc = a0*Bp[0] + a1*Bp[256] + a2*Bp[512];                          \
        acc += __shfl_down(acc, 32); acc += __shfl_down(acc, 16);                \
        acc += __shfl_down(acc, 8);  acc += __shfl_down(acc, 4);                 \
        acc += __shfl_down(acc, 2);  acc += __shfl_down(acc, 1);                 \
        if (lane == 0) scr[k][wave] = acc; }
    FOR8(GDOT)
#undef GDOT
    __syncthreads();
    if (tid < 8) G[ji*8 + tid] = scr[tid][0] + scr[tid][1] + scr[tid][2] + scr[tid][3];
}

// ---------------- kernel 3c: per-n dots dmq[n][ji] = M_ji . q'_nj + q' stats ----
__global__ __launch_bounds__(256) void k_dots(const float* __restrict__ H,
                                              const float* __restrict__ hm,
                                              float* __restrict__ dmq,
                                              float* __restrict__ Sq0v,
                                              float* __restrict__ Sq20v)
{
    const int j = blockIdx.x;           // 0..7
    const int tile = blockIdx.y;        // 0..7 (50 n each)
    const int tid = threadIdx.x;
    const int lane = tid & 63, wave = tid >> 6;   // 4 waves
    __shared__ __align__(16) float Ms[8][768];
    #pragma unroll
    for (int r = 0; r < 8; ++r)
        for (int c = tid; c < DD; c += 256)
            Ms[r][c] = hm[(size_t)(j*8 + r)*DD + c];
    __syncthreads();

    for (int nn = wave; nn < 50; nn += 4) {
        const int n = tile * 50 + nn;
        const float* qp = H + (size_t)n * JD + j * DD;
        float s = 0.f, s2 = 0.f;
#define DCL(k) float d##k = 0.f;
        FOR8(DCL)
#undef DCL
        #pragma unroll 2
        for (int c = 0; c < 12; ++c) {
            const int d = lane + 64 * c;
            const float qv = qp[d];
            s += qv; s2 += qv * qv;
#define MAC(k) d##k += qv * Ms[k][d];
            FOR8(MAC)
#undef MAC
        }
#define XR(v) { v += __shfl_xor(v, 32); v += __shfl_xor(v, 16); v += __shfl_xor(v, 8); \
                v += __shfl_xor(v, 4);  v += __shfl_xor(v, 2);  v += __shfl_xor(v, 1); }
#define XRD(k) XR(d##k)
        FOR8(XRD)
#undef XRD
        XR(s) XR(s2)
#undef XR
        if (lane == 0) {
#define ST(k) dmq[(size_t)n*64 + j*8 + k] = d##k;
            FOR8(ST)
#undef ST
            Sq0v[n*8 + j] = s;
            Sq20v[n*8 + j] = s2;
        }
    }
}

// ---------------- kernel 4: fused routing (hmT-register passes) ----------------
__global__ __launch_bounds__(768) void k_route2(const float* __restrict__ H,
                                                const float* __restrict__ hm,
                                                const float* __restrict__ hmT,
                                                const float* __restrict__ muM,
                                                const float* __restrict__ mc2M,
                                                const float* __restrict__ G,
                                                const float* __restrict__ dmq,
                                                const float* __restrict__ Sq0v,
                                                const float* __restrict__ Sq20v,
                                                float* __restrict__ out)
{
    const int n = blockIdx.x;
    const int tid = threadIdx.x;                  // d
    const int lane = tid & 63, wave = tid >> 6;   // 12 waves
    __shared__ __align__(16) float sVv[8][768];
    __shared__ float scr[24][12];
    __shared__ float rstat[24];
    __shared__ float sDot[64];
    __shared__ float sP[64], sC1[64], sC2[64], sB1[64];

#define WRED(val, idx) { float _v = (val);                           \
    _v += __shfl_down(_v, 32); _v += __shfl_down(_v, 16);            \
    _v += __shfl_down(_v, 8);  _v += __shfl_down(_v, 4);             \
    _v += __shfl_down(_v, 2);  _v += __shfl_down(_v, 1);             \
    if (lane == 0) scr[(idx)][wave] = _v; }

#define FIN(nv) { if (tid < (nv)) { float _s = 0.f;                  \
    _Pragma("unroll")                                                \
    for (int _w = 0; _w < 12; ++_w) _s += scr[tid][_w];              \
    rstat[tid] = _s; } }

#define DOTLOOP() for (int t = wave; t < 64; t += 12) {              \
        const int _j = t >> 3;                                       \
        const float* Mrow = hm + (size_t)t * DD;                     \
        float acc = 0.f;                                             \
        _Pragma("unroll")                                            \
        for (int c = 0; c < 3; ++c) {                                \
            const int dd = c * 256 + lane * 4;                       \
            const float4 mv = *reinterpret_cast<const float4*>(Mrow + dd);       \
            const float4 vv = *reinterpret_cast<const float4*>(&sVv[_j][dd]);    \
            acc += mv.x*vv.x + mv.y*vv.y + mv.z*vv.z + mv.w*vv.w;    \
        }                                                            \
        acc += __shfl_down(acc, 32); acc += __shfl_down(acc, 16);    \
        acc += __shfl_down(acc, 8);  acc += __shfl_down(acc, 4);     \
        acc += __shfl_down(acc, 2);  acc += __shfl_down(acc, 1);     \
        if (lane == 0) sDot[t] = acc;                                \
    }

#define XR3(v) { v += __shfl_xor(v, 1); v += __shfl_xor(v, 2); v += __shfl_xor(v, 4); }

    // ---- stage 0 (wave 0): coefficient-space routing iteration 1 ----
    float w0 = 0.f, s1 = 0.f, dotM1 = 0.f, Sq1 = 0.f, Sq21 = 0.f, mu = 0.f, mc2 = 0.f;
    if (tid < 64) {
        const int j = lane >> 3;
        mu  = muM[lane];
        mc2 = mc2M[lane];
        const float smR = 768.f * mu;              // sum of M row
        const float dq  = dmq[(size_t)n * 64 + lane];
        const float Sq  = Sq0v[n * 8 + j];
        const float Sq2v = Sq20v[n * 8 + j];
        {
            float num  = dq - mu * Sq;
            float varq = fmaxf(Sq2v - Sq * Sq * (1.f / 768.f), 0.f);
            float den  = sqrtf(mc2 * varq) + EPSF;
            w0 = tanhf(num / den) + 0.125f;        // w0 = 1/8 + p0
        }
        const float* Gr = G + lane * 8;
        const int base = lane & ~7;
        float gw = 0.f;
        #pragma unroll
        for (int ii = 0; ii < 8; ++ii) gw += Gr[ii] * __shfl(w0, base + ii);
        float n2h1 = w0 * gw;  XR3(n2h1);          // |hv1|^2
        float dqh1 = w0 * dq;  XR3(dqh1);          // dot(q', hv1)
        float Sh1  = w0 * smR; XR3(Sh1);           // sum(hv1)
        s1 = n2h1 / ((1.f + n2h1) * sqrtf(n2h1 + EPSF));
        float c1 = s1 * gw;
        sC1[lane] = c1;
        sB1[lane] = 0.5f * s1 * w0;
        dotM1 = 0.5f * (dq + c1);
        Sq1   = 0.5f * (Sq + s1 * Sh1);
        Sq21  = 0.25f * (Sq2v + 2.f * s1 * dqh1 + s1 * s1 * n2h1);   // |tq1|^2
        float varq1 = fmaxf(Sq21 - Sq1 * Sq1 * (1.f / 768.f), 0.f);
        sP[lane] = tanhf((dotM1 - mu * Sq1) / (sqrtf(mc2 * varq1) + EPSF));  // p1
    }
    __syncthreads();

    // ---- pass 1 (d-space): hv2 + tq1 reconstruction, hm from hmT registers ----
    const float* Hn = H + (size_t)n * JD + tid;
    const float* hrow = hmT + (size_t)tid * 64;
#define DECL(k) float t0_##k = Hn[k * DD]; float tq1_##k = 0.5f * t0_##k; float vh_##k = 0.f;
    FOR8(DECL)
#undef DECL
    #pragma unroll 1
    for (int ih = 0; ih < 8; ih += 2) {
#define CH(k) const float2 h##k = *reinterpret_cast<const float2*>(hrow + k * 8 + ih);
        FOR8(CH)
#undef CH
        #pragma unroll
        for (int ii = 0; ii < 2; ++ii) {
            const int i = ih + ii;
#define XA(k) float x##k = t0_##k * sC1[k * 8 + i];
            FOR8(XA)
#undef XA
            float mx = fmaxf(fmaxf(fmaxf(x0, x1), fmaxf(x2, x3)),
                             fmaxf(fmaxf(x4, x5), fmaxf(x6, x7)));
#define XE(k) x##k = __expf(x##k - mx);
            FOR8(XE)
#undef XE
            float inv = 1.f / (x0 + x1 + x2 + x3 + x4 + x5 + x6 + x7);
#define XACC(k) { const float mval = ii ? h##k.y : h##k.x;           \
        vh_##k  += (x##k * inv + sP[k * 8 + i]) * mval;              \
        tq1_##k += sB1[k * 8 + i] * mval; }
            FOR8(XACC)
#undef XACC
        }
    }
#define STG(k) sVv[k][tid] = vh_##k;                                 \
    WRED(vh_##k * vh_##k, k); WRED(vh_##k, 8 + k); WRED(t0_##k * vh_##k, 16 + k);
    FOR8(STG)
#undef STG
    __syncthreads();
    // ---- pass 2: u[ji] = M_ji . hv2_j ----
    DOTLOOP();
    FIN(24);
    __syncthreads();

    // ---- stage 2 (wave 0): p2, c2 ----
    if (tid < 64) {
        const int j = lane >> 3;
        const float n2h2 = rstat[j];               // |hv2|^2
        const float Sh2  = rstat[8 + j];           // sum(hv2)
        const float dqh2 = rstat[16 + j];          // dot(q', hv2)
        const float u = sDot[lane];                // dot(M_ji, hv2_j)
        float s2 = n2h2 / ((1.f + n2h2) * sqrtf(n2h2 + EPSF));
        float c2 = s2 * u;
        sC2[lane] = c2;
        float dotM2 = 0.5f * (dotM1 + c2);
        float w0u = w0 * u; XR3(w0u);              // dot(hv1, hv2)
        float dt1h2 = 0.5f * (dqh2 + s1 * w0u);    // dot(tq1, hv2)
        float Sq2_ = 0.5f * (Sq1 + s2 * Sh2);
        float Sq22 = 0.25f * Sq21 + 0.5f * s2 * dt1h2 + 0.25f * s2 * s2 * n2h2;  // |tq2|^2
        float varq2 = fmaxf(Sq22 - Sq2_ * Sq2_ * (1.f / 768.f), 0.f);
        sP[lane] = tanhf((dotM2 - mu * Sq2_) / (sqrtf(mc2 * varq2) + EPSF));     // p2
    }
    __syncthreads();

    // ---- pass 3 (d-space): final softmax + hv3 + squash + write ----
#define ZV(k) vh_##k = 0.f;
    FOR8(ZV)
#undef ZV
    #pragma unroll 1
    for (int ih = 0; ih < 8; ih += 2) {
#define CH(k) const float2 h##k = *reinterpret_cast<const float2*>(hrow + k * 8 + ih);
        FOR8(CH)
#undef CH
        #pragma unroll
        for (int ii = 0; ii < 2; ++ii) {
            const int i = ih + ii;
#define XA(k) float x##k = t0_##k * sC1[k * 8 + i] + tq1_##k * sC2[k * 8 + i];
            FOR8(XA)
#undef XA
            float mx = fmaxf(fmaxf(fmaxf(x0, x1), fmaxf(x2, x3)),
                             fmaxf(fmaxf(x4, x5), fmaxf(x6, x7)));
#define XE(k) x##k = __expf(x##k - mx);
            FOR8(XE)
#undef XE
            float inv = 1.f / (x0 + x1 + x2 + x3 + x4 + x5 + x6 + x7);
#define XACC(k) { const float mval = ii ? h##k.y : h##k.x;           \
        vh_##k += (x##k * inv + sP[k * 8 + i]) * mval; }
            FOR8(XACC)
#undef XACC
        }
    }
#define NRM(k) WRED(vh_##k * vh_##k, k);
    FOR8(NRM)
#undef NRM
    __syncthreads();
    FIN(8);
    __syncthreads();
    float* On = out + (size_t)n * JD + tid;
#define WOUT(k) { float n2 = rstat[k];                               \
        float sc = n2 / ((1.f + n2) * sqrtf(n2 + EPSF));             \
        On[k * DD] = vh_##k * sc; }
    FOR8(WOUT)
#undef WOUT
#undef WRED
#undef FIN
#undef DOTLOOP
#undef XR3
}

extern "C" void kernel_launch(void* const* d_in, const int* in_sizes, int n_in,
                              void* d_out, int out_size, void* d_ws, size_t ws_size,
                              hipStream_t stream) {
    const float* m  = (const float*)d_in[0];   // [8,768]
    const float* q  = (const float*)d_in[1];   // [400,768]
    const float* W  = (const float*)d_in[2];   // [1,8,8,768,768]
    const float* b  = (const float*)d_in[3];   // [1,8,8,768]
    const float* Wn = (const float*)d_in[4];   // [768,768]
    float* out = (float*)d_out;
    float* ws  = (float*)d_ws;

    float* H     = ws + OFF_H;
    float* hm    = ws + OFF_HM;
    float* muM   = ws + OFF_MU;
    float* mc2M  = ws + OFF_MC2;
    float* G     = ws + OFF_G;
    float* dmq   = ws + OFF_DMQ;
    float* Sq0v  = ws + OFF_SQ0;
    float* Sq20v = ws + OFF_SQ20;
    float* hmT   = ws + OFF_HMT;
    unsigned short* A2 = (unsigned short*)(ws + OFF_A2);
    unsigned short* B2 = (unsigned short*)(ws + OFF_B2);

    k_cvtA<<<dim3(408), 256, 0, stream>>>(q, m, Wn, A2);
    k_cvtB<<<dim3(6144), 256, 0, stream>>>(W, B2);
    k_gemm_mfma<<<dim3(48, 4), 256, 0, stream>>>(A2, B2, H);
    k_prep<<<dim3(64), 256, 0, stream>>>(H, b, hm, hmT, muM, mc2M);
    k_gram<<<dim3(64), 256, 0, stream>>>(hm, G);
    k_dots<<<dim3(8, 8), 256, 0, stream>>>(H, hm, dmq, Sq0v, Sq20v);
    k_route2<<<dim3(400), 768, 0, stream>>>(H, hm, hmT, muM, mc2M, G, dmq, Sq0v, Sq20v, out);
}

// Round 8
// 147.900 us; speedup vs baseline: 1.4319x; 1.4319x over previous
//
#include <hip/hip_runtime.h>
#include <math.h>

#define DD    768
#define NQ    400
#define NROWS 408          // 400 q rows + 8 m_proj rows
#define JD    6144         // J*D = 8*768
#define WSLICE 4718592     // I*D*E = 8*768*768 (stride between j slices of W)
#define EPSF  1e-8f
#define K2    2304         // split-bf16 packed K (3 segments of 768)

// ---------------- workspace layout (floats) ----------------
#define OFF_H     0                       // [408][6144]
#define OFF_HM    (OFF_H + 408*6144)      // [64][768]  (j*8+i major)
#define OFF_MU    (OFF_HM + 64*768)       // [64]
#define OFF_MC2   (OFF_MU + 64)           // [64]
#define OFF_G     (OFF_MC2 + 64)          // [64][8]  Gram
#define OFF_DMQ   (OFF_G + 512)           // [400][64] dot(M_ji, q'_nj)
#define OFF_SQ0   (OFF_DMQ + 400*64)      // [400][8]  sum(q'_nj)
#define OFF_SQ20  (OFF_SQ0 + 400*8)       // [400][8]  sumsq(q'_nj)
#define OFF_A2    (OFF_SQ20 + 400*8)      // [512][2304] bf16 (as u16)
#define OFF_B2    (OFF_A2 + 512*K2/2)     // [6144][2304] bf16 (as u16)

#define FOR8(M) M(0) M(1) M(2) M(3) M(4) M(5) M(6) M(7)

typedef __attribute__((ext_vector_type(8))) short short8v;
typedef __attribute__((ext_vector_type(4))) float float4v;

__device__ inline unsigned short f2bf(float x) {
    unsigned u = __float_as_uint(x);
    u += 0x7FFF + ((u >> 16) & 1);
    return (unsigned short)(u >> 16);
}
__device__ inline float bf2f(unsigned short h) {
    return __uint_as_float(((unsigned)h) << 16);
}

// ---------------- kernel 1: pack A''=[hi|lo|hi] and B''=[hi|hi|lo] ------------
// blocks 0..407: A rows (rows 400..407 compute m_proj = m @ W_n in-register).
// blocks 408..1943: B, 4 rows each (6144 rows total).
__global__ __launch_bounds__(256) void k_cvt(const float* __restrict__ q,
                                             const float* __restrict__ m,
                                             const float* __restrict__ Wn,
                                             const float* __restrict__ W,
                                             unsigned short* __restrict__ A2,
                                             unsigned short* __restrict__ B2)
{
    const int bid = blockIdx.x;
    const int tid = threadIdx.x;
    if (bid < 408) {
        const int r = bid;
        unsigned short* dst = A2 + (size_t)r * K2;
        if (r < NQ) {
            const float* src = q + (size_t)r * DD;
            #pragma unroll
            for (int u0 = 0; u0 < 3; ++u0) {
                const int u = u0 * 256 + tid;
                float x = src[u];
                unsigned short hi = f2bf(x);
                unsigned short lo = f2bf(x - bf2f(hi));
                dst[u] = hi; dst[DD + u] = lo; dst[2*DD + u] = hi;
            }
        } else {
            const int i = r - NQ;
            float a0 = 0.f, a1 = 0.f, a2 = 0.f;
            #pragma unroll 8
            for (int e = 0; e < DD; ++e) {
                const float mv = m[i*DD + e];
                const float* wr = Wn + (size_t)e * DD;
                a0 += mv * wr[tid];
                a1 += mv * wr[tid + 256];
                a2 += mv * wr[tid + 512];
            }
            #pragma unroll
            for (int u0 = 0; u0 < 3; ++u0) {
                const int u = u0 * 256 + tid;
                float x = (u0 == 0) ? a0 : (u0 == 1) ? a1 : a2;
                unsigned short hi = f2bf(x);
                unsigned short lo = f2bf(x - bf2f(hi));
                dst[u] = hi; dst[DD + u] = lo; dst[2*DD + u] = hi;
            }
        }
    } else {
        const int r0 = (bid - 408) * 4;
        #pragma unroll
        for (int rr = 0; rr < 4; ++rr) {
            const int rw = r0 + rr;
            const int jj = rw / 768;
            const int d  = rw - jj * 768;
            const float* src = W + (size_t)jj * WSLICE + (size_t)d * DD;
            unsigned short* dst = B2 + (size_t)rw * K2;
            #pragma unroll
            for (int u0 = 0; u0 < 3; ++u0) {
                const int u = u0 * 256 + tid;
                float x = src[u];
                unsigned short hi = f2bf(x);
                unsigned short lo = f2bf(x - bf2f(hi));
                dst[u] = hi; dst[DD + u] = hi; dst[2*DD + u] = lo;
            }
        }
    }
}

// ---------------- kernel 2: MFMA GEMM, BM=128 x BN=64, 2-phase dbuf -----------
__global__ __launch_bounds__(256) void k_gemm_mfma(const unsigned short* __restrict__ A2,
                                                   const unsigned short* __restrict__ B2,
                                                   float* __restrict__ H)
{
    __shared__ __align__(16) unsigned short lds[2][12288];  // A:[0,8192) B:[8192,12288)
    const int tid = threadIdx.x;
    const int wv  = tid >> 6;
    const int ln  = tid & 63;
    const int c0  = blockIdx.x * 64;       // 0..6143, never straddles a j
    const int m0  = blockIdx.y * 128;
    const int wm  = (wv >> 1) * 64;        // 0 / 64
    const int wn  = (wv & 1) * 32;         // 0 / 32
    const unsigned short* Ap = A2 + (size_t)m0 * K2;
    const unsigned short* Bp = B2 + (size_t)c0 * K2;

    float4v acc[4][2];
    #pragma unroll
    for (int a = 0; a < 4; ++a)
        #pragma unroll
        for (int b = 0; b < 2; ++b)
            acc[a][b] = (float4v){0.f, 0.f, 0.f, 0.f};

#define STAGE(buf, kk0) {                                                         \
    _Pragma("unroll")                                                             \
    for (int qq = 0; qq < 4; ++qq) {                                              \
        const int idx = (qq << 8) + tid;          /* 0..1023 */                   \
        const int row = idx >> 3;                 /* 0..127 */                    \
        const int ce  = ((idx & 7) ^ (row & 7)) << 3;                             \
        __builtin_amdgcn_global_load_lds(                                         \
            (const __attribute__((address_space(1))) void*)(Ap + (size_t)row * K2 + (kk0) + ce), \
            (__attribute__((address_space(3))) void*)(&lds[buf][idx * 8]), 16, 0, 0);            \
    }                                                                             \
    _Pragma("unroll")                                                             \
    for (int qq = 0; qq < 2; ++qq) {                                              \
        const int idx = (qq << 8) + tid;          /* 0..511 */                    \
        const int row = idx >> 3;                 /* 0..63 */                     \
        const int ce  = ((idx & 7) ^ (row & 7)) << 3;                             \
        __builtin_amdgcn_global_load_lds(                                         \
            (const __attribute__((address_space(1))) void*)(Bp + (size_t)row * K2 + (kk0) + ce), \
            (__attribute__((address_space(3))) void*)(&lds[buf][8192 + idx * 8]), 16, 0, 0);     \
    } }

#define COMPUTE(buf) { _Pragma("unroll")                                          \
    for (int s = 0; s < 2; ++s) {                                                 \
        short8v af[4], bf[2];                                                     \
        _Pragma("unroll")                                                         \
        for (int mi = 0; mi < 4; ++mi) {                                          \
            const int row = wm + mi * 16 + (ln & 15);                             \
            const int off = row * 64 + ((s * 32 + ((ln >> 4) * 8)) ^ ((row & 7) << 3)); \
            af[mi] = *reinterpret_cast<const short8v*>(&lds[buf][off]);           \
        }                                                                         \
        _Pragma("unroll")                                                         \
        for (int ni = 0; ni < 2; ++ni) {                                          \
            const int row = wn + ni * 16 + (ln & 15);                             \
            const int off = row * 64 + ((s * 32 + ((ln >> 4) * 8)) ^ ((row & 7) << 3)); \
            bf[ni] = *reinterpret_cast<const short8v*>(&lds[buf][8192 + off]);    \
        }                                                                         \
        _Pragma("unroll")                                                         \
        for (int mi = 0; mi < 4; ++mi)                                            \
            _Pragma("unroll")                                                     \
            for (int ni = 0; ni < 2; ++ni)                                        \
                acc[mi][ni] = __builtin_amdgcn_mfma_f32_16x16x32_bf16(af[mi], bf[ni], acc[mi][ni], 0, 0, 0); \
    } }

    STAGE(0, 0);
    __syncthreads();
    int cur = 0;
    for (int k0 = 64; k0 < K2; k0 += 64) {
        STAGE(cur ^ 1, k0);
        COMPUTE(cur);
        __syncthreads();
        cur ^= 1;
    }
    COMPUTE(cur);
#undef STAGE
#undef COMPUTE

    #pragma unroll
    for (int mi = 0; mi < 4; ++mi) {
        #pragma unroll
        for (int r = 0; r < 4; ++r) {
            const int gr = m0 + wm + mi * 16 + (ln >> 4) * 4 + r;
            if (gr < NROWS) {
                #pragma unroll
                for (int ni = 0; ni < 2; ++ni)
                    H[(size_t)gr * JD + c0 + wn + ni * 16 + (ln & 15)] = acc[mi][ni][r];
            }
        }
    }
}

// ---------------- kernel 3: merged prep / gram / dots (concurrent roles) ------
// blocks 0..63:    prep  (hm = H_row+b, mu, mc2)
// blocks 64..127:  gram  (G; reconstructs hm = H+b on the fly)
// blocks 128..255: dots  (dmq + q' stats; 16 n-tiles x 8 j)
__global__ __launch_bounds__(256) void k_mid(const float* __restrict__ H,
                                             const float* __restrict__ b,
                                             float* __restrict__ hm,
                                             float* __restrict__ muM,
                                             float* __restrict__ mc2M,
                                             float* __restrict__ G,
                                             float* __restrict__ dmq,
                                             float* __restrict__ Sq0v,
                                             float* __restrict__ Sq20v)
{
    const int bid = blockIdx.x;
    const int tid = threadIdx.x;
    const int lane = tid & 63, wave = tid >> 6;
    __shared__ __align__(16) float Ms[8][768];     // dots staging (also scr reuse)
    __shared__ float scr[8][4];
    __shared__ float smu;

    if (bid < 64) {
        // ---------------- prep ----------------
        const int ji = bid;
        const int j = ji >> 3, i = ji & 7;
        float vals[3];
        float s = 0.f;
        #pragma unroll
        for (int u = 0; u < 3; ++u) {
            const int d = u * 256 + tid;
            float x = H[(size_t)(NQ + i) * JD + j * DD + d] + b[(size_t)ji * DD + d];
            hm[(size_t)ji * DD + d] = x;
            vals[u] = x;
            s += x;
        }
        #pragma unroll
        for (int off = 32; off; off >>= 1) s += __shfl_down(s, off);
        if (lane == 0) scr[0][wave] = s;
        __syncthreads();
        if (tid == 0) smu = (scr[0][0] + scr[0][1] + scr[0][2] + scr[0][3]) * (1.f / 768.f);
        __syncthreads();
        const float mu = smu;
        float s2 = 0.f;
        #pragma unroll
        for (int u = 0; u < 3; ++u) { float c = vals[u] - mu; s2 += c * c; }
        __syncthreads();
        #pragma unroll
        for (int off = 32; off; off >>= 1) s2 += __shfl_down(s2, off);
        if (lane == 0) scr[0][wave] = s2;
        __syncthreads();
        if (tid == 0) { muM[ji] = mu; mc2M[ji] = scr[0][0] + scr[0][1] + scr[0][2] + scr[0][3]; }
    } else if (bid < 128) {
        // ---------------- gram ----------------
        const int ji = bid - 64;
        const int j = ji >> 3, i = ji & 7;
        const float* Hj = H + j * DD;
        const float* bj = b + (size_t)(j * 8) * DD;
        const float a0 = Hj[(size_t)(NQ + i) * JD + tid]       + bj[(size_t)i * DD + tid];
        const float a1 = Hj[(size_t)(NQ + i) * JD + 256 + tid] + bj[(size_t)i * DD + 256 + tid];
        const float a2 = Hj[(size_t)(NQ + i) * JD + 512 + tid] + bj[(size_t)i * DD + 512 + tid];
#define GDOT(k) { const float* Hp = Hj + (size_t)(NQ + k) * JD + tid;            \
        const float* bp = bj + (size_t)k * DD + tid;                             \
        float acc = a0*(Hp[0]+bp[0]) + a1*(Hp[256]+bp[256]) + a2*(Hp[512]+bp[512]); \
        acc += __shfl_down(acc, 32); acc += __shfl_down(acc, 16);                \
        acc += __shfl_down(acc, 8);  acc += __shfl_down(acc, 4);                 \
        acc += __shfl_down(acc, 2);  acc += __shfl_down(acc, 1);                 \
        if (lane == 0) scr[k][wave] = acc; }
        FOR8(GDOT)
#undef GDOT
        __syncthreads();
        if (tid < 8) G[ji*8 + tid] = scr[tid][0] + scr[tid][1] + scr[tid][2] + scr[tid][3];
    } else {
        // ---------------- dots ----------------
        const int t = bid - 128;
        const int j = t & 7;
        const int tile = t >> 3;            // 0..15, 25 n each
        #pragma unroll
        for (int r = 0; r < 8; ++r)
            for (int c = tid; c < DD; c += 256)
                Ms[r][c] = H[(size_t)(NQ + r) * JD + j * DD + c] + b[(size_t)(j * 8 + r) * DD + c];
        __syncthreads();

        for (int nn = wave; nn < 25; nn += 4) {
            const int n = tile * 25 + nn;
            const float* qp = H + (size_t)n * JD + j * DD;
            float s = 0.f, s2 = 0.f;
#define DCL(k) float d##k = 0.f;
            FOR8(DCL)
#undef DCL
            #pragma unroll 2
            for (int c = 0; c < 12; ++c) {
                const int d = lane + 64 * c;
                const float qv = qp[d];
                s += qv; s2 += qv * qv;
#define MAC(k) d##k += qv * Ms[k][d];
                FOR8(MAC)
#undef MAC
            }
#define XR(v) { v += __shfl_xor(v, 32); v += __shfl_xor(v, 16); v += __shfl_xor(v, 8); \
                v += __shfl_xor(v, 4);  v += __shfl_xor(v, 2);  v += __shfl_xor(v, 1); }
#define XRD(k) XR(d##k)
            FOR8(XRD)
#undef XRD
            XR(s) XR(s2)
#undef XR
            if (lane == 0) {
#define ST(k) dmq[(size_t)n*64 + j*8 + k] = d##k;
                FOR8(ST)
#undef ST
                Sq0v[n*8 + j] = s;
                Sq20v[n*8 + j] = s2;
            }
        }
    }
}

// ---------------- kernel 4: fused routing (R6 coalesced pattern + __expf) -----
__global__ __launch_bounds__(768) void k_route2(const float* __restrict__ H,
                                                const float* __restrict__ hm,
                                                const float* __restrict__ muM,
                                                const float* __restrict__ mc2M,
                                                const float* __restrict__ G,
                                                const float* __restrict__ dmq,
                                                const float* __restrict__ Sq0v,
                                                const float* __restrict__ Sq20v,
                                                float* __restrict__ out)
{
    const int n = blockIdx.x;
    const int tid = threadIdx.x;                  // d
    const int lane = tid & 63, wave = tid >> 6;   // 12 waves
    __shared__ __align__(16) float sVv[8][768];
    __shared__ float scr[24][12];
    __shared__ float rstat[24];
    __shared__ float sDot[64];
    __shared__ float sP[64], sC1[64], sC2[64], sB1[64];

#define WRED(val, idx) { float _v = (val);                           \
    _v += __shfl_down(_v, 32); _v += __shfl_down(_v, 16);            \
    _v += __shfl_down(_v, 8);  _v += __shfl_down(_v, 4);             \
    _v += __shfl_down(_v, 2);  _v += __shfl_down(_v, 1);             \
    if (lane == 0) scr[(idx)][wave] = _v; }

#define FIN(nv) { if (tid < (nv)) { float _s = 0.f;                  \
    _Pragma("unroll")                                                \
    for (int _w = 0; _w < 12; ++_w) _s += scr[tid][_w];              \
    rstat[tid] = _s; } }

#define DOTLOOP() for (int t = wave; t < 64; t += 12) {              \
        const int _j = t >> 3;                                       \
        const float* Mrow = hm + (size_t)t * DD;                     \
        float acc = 0.f;                                             \
        _Pragma("unroll")                                            \
        for (int c = 0; c < 3; ++c) {                                \
            const int dd = c * 256 + lane * 4;                       \
            const float4 mv = *reinterpret_cast<const float4*>(Mrow + dd);       \
            const float4 vv = *reinterpret_cast<const float4*>(&sVv[_j][dd]);    \
            acc += mv.x*vv.x + mv.y*vv.y + mv.z*vv.z + mv.w*vv.w;    \
        }                                                            \
        acc += __shfl_down(acc, 32); acc += __shfl_down(acc, 16);    \
        acc += __shfl_down(acc, 8);  acc += __shfl_down(acc, 4);     \
        acc += __shfl_down(acc, 2);  acc += __shfl_down(acc, 1);     \
        if (lane == 0) sDot[t] = acc;                                \
    }

#define XR3(v) { v += __shfl_xor(v, 1); v += __shfl_xor(v, 2); v += __shfl_xor(v, 4); }

    // ---- stage 0 (wave 0): coefficient-space routing iteration 1 ----
    float w0 = 0.f, s1 = 0.f, dotM1 = 0.f, Sq1 = 0.f, Sq21 = 0.f, mu = 0.f, mc2 = 0.f;
    if (tid < 64) {
        const int j = lane >> 3;
        mu  = muM[lane];
        mc2 = mc2M[lane];
        const float smR = 768.f * mu;              // sum of M row
        const float dq  = dmq[(size_t)n * 64 + lane];
        const float Sq  = Sq0v[n * 8 + j];
        const float Sq2v = Sq20v[n * 8 + j];
        {
            float num  = dq - mu * Sq;
            float varq = fmaxf(Sq2v - Sq * Sq * (1.f / 768.f), 0.f);
            float den  = sqrtf(mc2 * varq) + EPSF;
            w0 = tanhf(num / den) + 0.125f;        // w0 = 1/8 + p0
        }
        const float* Gr = G + lane * 8;
        const int base = lane & ~7;
        float gw = 0.f;
        #pragma unroll
        for (int ii = 0; ii < 8; ++ii) gw += Gr[ii] * __shfl(w0, base + ii);
        float n2h1 = w0 * gw;  XR3(n2h1);          // |hv1|^2
        float dqh1 = w0 * dq;  XR3(dqh1);          // dot(q', hv1)
        float Sh1  = w0 * smR; XR3(Sh1);           // sum(hv1)
        s1 = n2h1 / ((1.f + n2h1) * sqrtf(n2h1 + EPSF));
        float c1 = s1 * gw;
        sC1[lane] = c1;
        sB1[lane] = 0.5f * s1 * w0;
        dotM1 = 0.5f * (dq + c1);
        Sq1   = 0.5f * (Sq + s1 * Sh1);
        Sq21  = 0.25f * (Sq2v + 2.f * s1 * dqh1 + s1 * s1 * n2h1);   // |tq1|^2
        float varq1 = fmaxf(Sq21 - Sq1 * Sq1 * (1.f / 768.f), 0.f);
        sP[lane] = tanhf((dotM1 - mu * Sq1) / (sqrtf(mc2 * varq1) + EPSF));  // p1
    }
    __syncthreads();

    // ---- pass 1 (d-space): hv2 + tq1 reconstruction (coalesced hm reads) ----
    const float* Hn = H + (size_t)n * JD + tid;
    const float* hmp = hm + tid;
#define DECL(k) float t0_##k = Hn[k * DD]; float tq1_##k = 0.5f * t0_##k; float vh_##k = 0.f;
    FOR8(DECL)
#undef DECL
    #pragma unroll 1
    for (int i = 0; i < 8; ++i) {
#define XA(k) float x##k = t0_##k * sC1[k * 8 + i];
        FOR8(XA)
#undef XA
        float mx = fmaxf(fmaxf(fmaxf(x0, x1), fmaxf(x2, x3)),
                         fmaxf(fmaxf(x4, x5), fmaxf(x6, x7)));
#define XE(k) x##k = __expf(x##k - mx);
        FOR8(XE)
#undef XE
        float inv = 1.f / (x0 + x1 + x2 + x3 + x4 + x5 + x6 + x7);
#define XACC(k) { const float mval = hmp[(size_t)(k * 8 + i) * DD];  \
        vh_##k  += (x##k * inv + sP[k * 8 + i]) * mval;              \
        tq1_##k += sB1[k * 8 + i] * mval; }
        FOR8(XACC)
#undef XACC
    }
#define STG(k) sVv[k][tid] = vh_##k;                                 \
    WRED(vh_##k * vh_##k, k); WRED(vh_##k, 8 + k); WRED(t0_##k * vh_##k, 16 + k);
    FOR8(STG)
#undef STG
    __syncthreads();
    // ---- pass 2: u[ji] = M_ji . hv2_j ----
    DOTLOOP();
    FIN(24);
    __syncthreads();

    // ---- stage 2 (wave 0): p2, c2 ----
    if (tid < 64) {
        const int j = lane >> 3;
        const float n2h2 = rstat[j];               // |hv2|^2
        const float Sh2  = rstat[8 + j];           // sum(hv2)
        const float dqh2 = rstat[16 + j];          // dot(q', hv2)
        const float u = sDot[lane];                // dot(M_ji, hv2_j)
        float s2 = n2h2 / ((1.f + n2h2) * sqrtf(n2h2 + EPSF));
        float c2 = s2 * u;
        sC2[lane] = c2;
        float dotM2 = 0.5f * (dotM1 + c2);
        float w0u = w0 * u; XR3(w0u);              // dot(hv1, hv2)
        float dt1h2 = 0.5f * (dqh2 + s1 * w0u);    // dot(tq1, hv2)
        float Sq2_ = 0.5f * (Sq1 + s2 * Sh2);
        float Sq22 = 0.25f * Sq21 + 0.5f * s2 * dt1h2 + 0.25f * s2 * s2 * n2h2;  // |tq2|^2
        float varq2 = fmaxf(Sq22 - Sq2_ * Sq2_ * (1.f / 768.f), 0.f);
        sP[lane] = tanhf((dotM2 - mu * Sq2_) / (sqrtf(mc2 * varq2) + EPSF));     // p2
    }
    __syncthreads();

    // ---- pass 3 (d-space): final softmax + hv3 + squash + write ----
#define ZV(k) vh_##k = 0.f;
    FOR8(ZV)
#undef ZV
    #pragma unroll 1
    for (int i = 0; i < 8; ++i) {
#define XA(k) float x##k = t0_##k * sC1[k * 8 + i] + tq1_##k * sC2[k * 8 + i];
        FOR8(XA)
#undef XA
        float mx = fmaxf(fmaxf(fmaxf(x0, x1), fmaxf(x2, x3)),
                         fmaxf(fmaxf(x4, x5), fmaxf(x6, x7)));
#define XE(k) x##k = __expf(x##k - mx);
        FOR8(XE)
#undef XE
        float inv = 1.f / (x0 + x1 + x2 + x3 + x4 + x5 + x6 + x7);
#define XACC(k) vh_##k += (x##k * inv + sP[k * 8 + i]) * hmp[(size_t)(k * 8 + i) * DD];
        FOR8(XACC)
#undef XACC
    }
#define NRM(k) WRED(vh_##k * vh_##k, k);
    FOR8(NRM)
#undef NRM
    __syncthreads();
    FIN(8);
    __syncthreads();
    float* On = out + (size_t)n * JD + tid;
#define WOUT(k) { float n2 = rstat[k];                               \
        float sc = n2 / ((1.f + n2) * sqrtf(n2 + EPSF));             \
        On[k * DD] = vh_##k * sc; }
    FOR8(WOUT)
#undef WOUT
#undef WRED
#undef FIN
#undef DOTLOOP
#undef XR3
}

extern "C" void kernel_launch(void* const* d_in, const int* in_sizes, int n_in,
                              void* d_out, int out_size, void* d_ws, size_t ws_size,
                              hipStream_t stream) {
    const float* m  = (const float*)d_in[0];   // [8,768]
    const float* q  = (const float*)d_in[1];   // [400,768]
    const float* W  = (const float*)d_in[2];   // [1,8,8,768,768]
    const float* b  = (const float*)d_in[3];   // [1,8,8,768]
    const float* Wn = (const float*)d_in[4];   // [768,768]
    float* out = (float*)d_out;
    float* ws  = (float*)d_ws;

    float* H     = ws + OFF_H;
    float* hm    = ws + OFF_HM;
    float* muM   = ws + OFF_MU;
    float* mc2M  = ws + OFF_MC2;
    float* G     = ws + OFF_G;
    float* dmq   = ws + OFF_DMQ;
    float* Sq0v  = ws + OFF_SQ0;
    float* Sq20v = ws + OFF_SQ20;
    unsigned short* A2 = (unsigned short*)(ws + OFF_A2);
    unsigned short* B2 = (unsigned short*)(ws + OFF_B2);

    k_cvt<<<dim3(1944), 256, 0, stream>>>(q, m, Wn, W, A2, B2);
    k_gemm_mfma<<<dim3(96, 4), 256, 0, stream>>>(A2, B2, H);
    k_mid<<<dim3(256), 256, 0, stream>>>(H, b, hm, muM, mc2M, G, dmq, Sq0v, Sq20v);
    k_route2<<<dim3(400), 768, 0, stream>>>(H, hm, muM, mc2M, G, dmq, Sq0v, Sq20v, out);
}